// Round 1
// baseline (126.703 us; speedup 1.0000x reference)
//
#include <hip/hip_runtime.h>
#include <hip/hip_bf16.h>
#include <stdint.h>

typedef __attribute__((ext_vector_type(8))) short bf16x8;
typedef __attribute__((ext_vector_type(4))) float f32x4;

// Problem constants: source/target (256,256,16,16) fp32.
// P = 16*16 = 256 positions, I = 512 rows (concat), C = 256 channels.
#define NPOS 256
#define NROW 512
#define NCH  256

// ---------------------------------------------------------------------------
// Kernel 1: repack fp32 [i][c][p] -> bf16 X[p][i][c]   (LDS tile transpose)
// grid: 512 i * 4 cblk * 4 pblk = 8192 blocks, 256 threads
// ---------------------------------------------------------------------------
__global__ __launch_bounds__(256) void k_repack(const float* __restrict__ src,
                                                const float* __restrict__ tgt,
                                                unsigned short* __restrict__ X) {
  __shared__ float tile[64 * 65];  // [c][p], +1 pad breaks transpose conflicts
  int bx = blockIdx.x;
  int i  = bx >> 4;
  int cb = (bx >> 2) & 3;
  int pb = bx & 3;
  int c0 = cb * 64, p0 = pb * 64;
  const float* base = (i < 256) ? (src + (size_t)i * 65536)
                                : (tgt + (size_t)(i - 256) * 65536);
  int t = threadIdx.x;
#pragma unroll
  for (int it = 0; it < 16; ++it) {
    int idx = it * 256 + t;
    int cl = idx >> 6, pl = idx & 63;                 // consecutive t -> consecutive p (coalesced)
    tile[cl * 65 + pl] = base[(c0 + cl) * 256 + p0 + pl];
  }
  __syncthreads();
#pragma unroll
  for (int it = 0; it < 16; ++it) {
    int idx = it * 256 + t;
    int pl = idx >> 6, cl = idx & 63;                 // consecutive t -> consecutive c (coalesced)
    float f = tile[cl * 65 + pl];
    unsigned u = __float_as_uint(f);
    unsigned r = (u + 0x7fffu + ((u >> 16) & 1u)) >> 16;   // RNE to bf16
    X[((size_t)(p0 + pl) * NROW + i) * NCH + c0 + cl] = (unsigned short)r;
  }
}

// ---------------------------------------------------------------------------
// Kernel 2: SQ[p*512+i] = sum_c X[p][i][c]^2  (one wave per row)
// grid: 131072 rows / 4 waves = 32768 blocks, 256 threads
// ---------------------------------------------------------------------------
__global__ __launch_bounds__(256) void k_sq(const unsigned short* __restrict__ X,
                                            float* __restrict__ SQ) {
  int w = (blockIdx.x * 256 + threadIdx.x) >> 6;   // global row 0..131071
  int lane = threadIdx.x & 63;
  const unsigned short* row = X + (size_t)w * NCH + lane * 4;
  ushort4 v = *(const ushort4*)row;
  float f0 = __uint_as_float((unsigned)v.x << 16);
  float f1 = __uint_as_float((unsigned)v.y << 16);
  float f2 = __uint_as_float((unsigned)v.z << 16);
  float f3 = __uint_as_float((unsigned)v.w << 16);
  float s = f0 * f0 + f1 * f1 + f2 * f2 + f3 * f3;
#pragma unroll
  for (int off = 32; off; off >>= 1) s += __shfl_down(s, off, 64);
  if (lane == 0) SQ[w] = s;
}

// ---------------------------------------------------------------------------
// Kernel 3: fused Gram + RBF-sum epilogue.
// grid: 256 pos * 16 tiles(128x128) = 4096 blocks, 256 threads (4 waves 2x2).
// LDS XOR-swizzle (both write AND read sides; reg-staged so this is legal).
// ---------------------------------------------------------------------------
__device__ __forceinline__ int swz(int row, int byteoff) {
  return row * 128 + (byteoff ^ ((row & 7) << 4));
}

__global__ __launch_bounds__(256) void k_mmd(const unsigned short* __restrict__ X,
                                             const float* __restrict__ SQ,
                                             float* __restrict__ part) {
  __shared__ unsigned short As[128 * 64];
  __shared__ unsigned short Bs[128 * 64];
  __shared__ float SQi[128], SQj[128];
  __shared__ float wsum[4];

  int bx = blockIdx.x;
  int p = bx >> 4;
  int tileid = bx & 15;
  int it = tileid >> 2, jt = tileid & 3;
  int i0 = it * 128, j0 = jt * 128;
  int t = threadIdx.x;
  int lane = t & 63, w = t >> 6;
  int wr = w >> 1, wc = w & 1;
  int l15 = lane & 15, lk = lane >> 4;

  const unsigned short* Xp = X + (size_t)p * (NROW * NCH);

  if (t < 128) SQi[t] = SQ[p * NROW + i0 + t];
  else         SQj[t - 128] = SQ[p * NROW + j0 + (t - 128)];

  f32x4 zero = {0.f, 0.f, 0.f, 0.f};
  f32x4 acc[4][4];
#pragma unroll
  for (int m = 0; m < 4; ++m)
#pragma unroll
    for (int n = 0; n < 4; ++n) acc[m][n] = zero;

  for (int kk = 0; kk < 4; ++kk) {
    // stage 128x64 bf16 A and B tiles (16B chunks, coalesced, swizzled dest)
#pragma unroll
    for (int itr = 0; itr < 4; ++itr) {
      int chunk = itr * 256 + t;
      int row = chunk >> 3, c8 = chunk & 7;
      uint4 va = *(const uint4*)&Xp[(size_t)(i0 + row) * NCH + kk * 64 + c8 * 8];
      uint4 vb = *(const uint4*)&Xp[(size_t)(j0 + row) * NCH + kk * 64 + c8 * 8];
      *(uint4*)((char*)As + swz(row, c8 * 16)) = va;
      *(uint4*)((char*)Bs + swz(row, c8 * 16)) = vb;
    }
    __syncthreads();
#pragma unroll
    for (int ks = 0; ks < 2; ++ks) {
      bf16x8 a[4], b[4];
#pragma unroll
      for (int m = 0; m < 4; ++m)
        a[m] = *(const bf16x8*)((const char*)As + swz(wr * 64 + m * 16 + l15, ks * 64 + lk * 16));
#pragma unroll
      for (int n = 0; n < 4; ++n)
        b[n] = *(const bf16x8*)((const char*)Bs + swz(wc * 64 + n * 16 + l15, ks * 64 + lk * 16));
#pragma unroll
      for (int m = 0; m < 4; ++m)
#pragma unroll
        for (int n = 0; n < 4; ++n)
          acc[m][n] = __builtin_amdgcn_mfma_f32_16x16x32_bf16(a[m], b[n], acc[m][n], 0, 0, 0);
    }
    __syncthreads();
  }

  // epilogue: D = sqi + sqj - 2c ; K = sum_b exp(-D/b) via 1 exp2 + squarings
  const float c80 = 0.01803368801f;  // log2(e)/80
  float sqi[16], sqj[4];
#pragma unroll
  for (int m = 0; m < 4; ++m)
#pragma unroll
    for (int r = 0; r < 4; ++r) sqi[m * 4 + r] = SQi[wr * 64 + m * 16 + lk * 4 + r];
#pragma unroll
  for (int n = 0; n < 4; ++n) sqj[n] = SQj[wc * 64 + n * 16 + l15];

  bool diag = (it == jt);
  float lsum = 0.f;
#pragma unroll
  for (int m = 0; m < 4; ++m) {
#pragma unroll
    for (int n = 0; n < 4; ++n) {
#pragma unroll
      for (int r = 0; r < 4; ++r) {
        float cv = acc[m][n][r];
        float D = sqi[m * 4 + r] + sqj[n] - 2.f * cv;
        float e80 = exp2f(-c80 * D);     // exp(-D/80)
        float e40 = e80 * e80;
        float e20 = e40 * e40;
        float e10 = e20 * e20;
        float e5  = e10 * e10;
        float e2  = e5 * e5 * e10;       // exp(-D(1/5+1/5+1/10)) = exp(-D/2)
        float K = (e80 + e40) + (e20 + e10) + (e5 + e2);
        if (diag) {
          int gi = wr * 64 + m * 16 + lk * 4 + r;   // C/D map: col=lane&15, row=(lane>>4)*4+reg
          int gj = wc * 64 + n * 16 + l15;
          if (gi == gj) K = 6.0f;                   // D==0 exactly on the diagonal
        }
        lsum += K;
      }
    }
  }
#pragma unroll
  for (int off = 32; off; off >>= 1) lsum += __shfl_down(lsum, off, 64);
  if (lane == 0) wsum[w] = lsum;
  __syncthreads();
  if (t == 0) {
    float s = wsum[0] + wsum[1] + wsum[2] + wsum[3];
    float sign = ((it < 2) == (jt < 2)) ? 1.0f : -1.0f;  // s_i * s_j, uniform per tile
    part[bx] = sign * s;
  }
}

// ---------------------------------------------------------------------------
// Kernel 4: deterministic final reduce of 4096 partials -> mean
// ---------------------------------------------------------------------------
__global__ __launch_bounds__(256) void k_reduce(const float* __restrict__ part,
                                                float* __restrict__ out) {
  __shared__ float wsum[4];
  int t = threadIdx.x;
  float s = 0.f;
#pragma unroll
  for (int i = 0; i < 16; ++i) s += part[i * 256 + t];
#pragma unroll
  for (int off = 32; off; off >>= 1) s += __shfl_down(s, off, 64);
  int lane = t & 63, w = t >> 6;
  if (lane == 0) wsum[w] = s;
  __syncthreads();
  if (t == 0) out[0] = (wsum[0] + wsum[1] + wsum[2] + wsum[3]) * (1.0f / 16777216.0f);
}

extern "C" void kernel_launch(void* const* d_in, const int* in_sizes, int n_in,
                              void* d_out, int out_size, void* d_ws, size_t ws_size,
                              hipStream_t stream) {
  (void)in_sizes; (void)n_in; (void)out_size; (void)ws_size;
  const float* src = (const float*)d_in[0];
  const float* tgt = (const float*)d_in[1];
  char* ws = (char*)d_ws;
  unsigned short* X = (unsigned short*)ws;                    // 67,108,864 B
  float* SQ   = (float*)(ws + 67108864);                      //    524,288 B
  float* PART = (float*)(ws + 67108864 + 524288);             //     16,384 B

  hipLaunchKernelGGL(k_repack, dim3(8192), dim3(256), 0, stream, src, tgt, X);
  hipLaunchKernelGGL(k_sq,     dim3(32768), dim3(256), 0, stream, X, SQ);
  hipLaunchKernelGGL(k_mmd,    dim3(4096), dim3(256), 0, stream, X, SQ, PART);
  hipLaunchKernelGGL(k_reduce, dim3(1),    dim3(256), 0, stream, PART, (float*)d_out);
}

// Round 2
// 93.805 us; speedup vs baseline: 1.3507x; 1.3507x over previous
//
#include <hip/hip_runtime.h>
#include <hip/hip_bf16.h>
#include <stdint.h>

typedef __attribute__((ext_vector_type(8))) short bf16x8;
typedef __attribute__((ext_vector_type(4))) float f32x4;

#define NPOS 256
#define NROW 512
#define NCH  256

// ---------------------------------------------------------------------------
// Kernel 1: repack fp32 [i][c][p] -> bf16 X[p][i][c]   (LDS tile transpose)
// grid: 512 i * 4 cblk * 4 pblk = 8192 blocks, 256 threads. float4 both ways.
// ---------------------------------------------------------------------------
__global__ __launch_bounds__(256) void k_repack(const float* __restrict__ src,
                                                const float* __restrict__ tgt,
                                                unsigned short* __restrict__ X) {
  __shared__ float tile[64 * 65];  // [c][p], +1 pad
  int bx = blockIdx.x;
  int i  = bx >> 4;
  int cb = (bx >> 2) & 3;
  int pb = bx & 3;
  int c0 = cb * 64, p0 = pb * 64;
  const float* base = (i < 256) ? (src + (size_t)i * 65536)
                                : (tgt + (size_t)(i - 256) * 65536);
  int t = threadIdx.x;
#pragma unroll
  for (int it = 0; it < 4; ++it) {
    int idx = it * 256 + t;
    int cl = idx >> 4, pq = idx & 15;                // float4 along p (coalesced)
    float4 v = *(const float4*)&base[(c0 + cl) * 256 + p0 + pq * 4];
    tile[cl * 65 + pq * 4 + 0] = v.x;
    tile[cl * 65 + pq * 4 + 1] = v.y;
    tile[cl * 65 + pq * 4 + 2] = v.z;
    tile[cl * 65 + pq * 4 + 3] = v.w;
  }
  __syncthreads();
#pragma unroll
  for (int it = 0; it < 4; ++it) {
    int idx = it * 256 + t;
    int pl = idx >> 4, cq = idx & 15;                // ushort4 along c (coalesced)
    ushort4 o;
    unsigned short* op = &o.x;
#pragma unroll
    for (int j = 0; j < 4; ++j) {
      unsigned u = __float_as_uint(tile[(cq * 4 + j) * 65 + pl]);
      op[j] = (unsigned short)((u + 0x7fffu + ((u >> 16) & 1u)) >> 16);  // RNE
    }
    *(ushort4*)&X[((size_t)(p0 + pl) * NROW + i) * NCH + c0 + cq * 4] = o;
  }
}

// ---------------------------------------------------------------------------
// Kernel 2: SQ[p*512+i] = sum_c X[p][i][c]^2  (half-wave per row, uint4 loads)
// grid: 131072 rows / 8 = 16384 blocks, 256 threads
// ---------------------------------------------------------------------------
__global__ __launch_bounds__(256) void k_sq(const unsigned short* __restrict__ X,
                                            float* __restrict__ SQ) {
  int gid = blockIdx.x * 256 + threadIdx.x;
  int row = gid >> 5;
  int l = threadIdx.x & 31;
  uint4 v = *(const uint4*)(X + (size_t)row * NCH + l * 8);
  float s = 0.f;
  const unsigned* u = &v.x;
#pragma unroll
  for (int j = 0; j < 4; ++j) {
    float flo = __uint_as_float(u[j] << 16);
    float fhi = __uint_as_float(u[j] & 0xffff0000u);
    s += flo * flo + fhi * fhi;
  }
#pragma unroll
  for (int off = 16; off; off >>= 1) s += __shfl_down(s, off, 32);
  if (l == 0) SQ[row] = s;
}

// ---------------------------------------------------------------------------
// Kernel 3: fused Gram + RBF-sum epilogue, upper-triangle tiles only.
// grid: 256 pos * 10 tiles(128x128) = 2560 blocks, 256 threads (4 waves 2x2).
// Staging: global_load_lds w=16, linear LDS dest + inverse-swizzled source;
// reads use the XOR swizzle (involution) -> conflict-free, no reg round-trip.
// ---------------------------------------------------------------------------
__device__ __forceinline__ int swz(int row, int byteoff) {
  return row * 128 + (byteoff ^ ((row & 7) << 4));
}

__global__ __launch_bounds__(256) void k_mmd(const unsigned short* __restrict__ X,
                                             const float* __restrict__ SQ,
                                             float* __restrict__ part) {
  __shared__ unsigned short As[128 * 64];
  __shared__ unsigned short Bs[128 * 64];
  __shared__ float SQi[128], SQj[128];
  __shared__ float wsum[4];

  int bid = blockIdx.x;
  int bx = (bid & 7) * 320 + (bid >> 3);   // XCD swizzle (bijective: 2560 = 8*320)
  int p = bx / 10;
  int tileid = bx - p * 10;
  int it, jt;
  if (tileid < 4)      { it = 0; jt = tileid; }
  else if (tileid < 7) { it = 1; jt = tileid - 3; }
  else if (tileid < 9) { it = 2; jt = tileid - 5; }
  else                 { it = 3; jt = 3; }
  int i0 = it * 128, j0 = jt * 128;
  int t = threadIdx.x;
  int lane = t & 63, w = t >> 6;
  int wr = w >> 1, wc = w & 1;
  int l15 = lane & 15, lk = lane >> 4;

  const unsigned short* Xp = X + (size_t)p * (NROW * NCH);
  const char* XA = (const char*)Xp + (size_t)i0 * 512;   // 512 B per row (256 bf16)
  const char* XB = (const char*)Xp + (size_t)j0 * 512;

  if (t < 128) SQi[t] = SQ[p * NROW + i0 + t];
  else         SQj[t - 128] = SQ[p * NROW + j0 + (t - 128)];

  f32x4 zero = {0.f, 0.f, 0.f, 0.f};
  f32x4 acc[4][4];
#pragma unroll
  for (int m = 0; m < 4; ++m)
#pragma unroll
    for (int n = 0; n < 4; ++n) acc[m][n] = zero;

  // per-lane constant source swizzle: row&7 == lane>>3 for every issued chunk
  int lrow = lane >> 3;                    // local row within 8-row group
  int coff = ((lane & 7) ^ lrow) * 16;     // inverse-swizzled 16B column

  for (int kk = 0; kk < 4; ++kk) {
#pragma unroll
    for (int s = 0; s < 4; ++s) {
      int rbase = w * 32 + s * 8;          // wave-uniform
      const char* ga = XA + (size_t)(rbase + lrow) * 512 + kk * 128 + coff;
      const char* gb = XB + (size_t)(rbase + lrow) * 512 + kk * 128 + coff;
      __builtin_amdgcn_global_load_lds(
          (const __attribute__((address_space(1))) void*)ga,
          (__attribute__((address_space(3))) void*)((char*)As + rbase * 128), 16, 0, 0);
      __builtin_amdgcn_global_load_lds(
          (const __attribute__((address_space(1))) void*)gb,
          (__attribute__((address_space(3))) void*)((char*)Bs + rbase * 128), 16, 0, 0);
    }
    __syncthreads();                       // drains vmcnt(0): staged data visible
#pragma unroll
    for (int ks = 0; ks < 2; ++ks) {
      bf16x8 a[4], b[4];
#pragma unroll
      for (int m = 0; m < 4; ++m)
        a[m] = *(const bf16x8*)((const char*)As + swz(wr * 64 + m * 16 + l15, ks * 64 + lk * 16));
#pragma unroll
      for (int n = 0; n < 4; ++n)
        b[n] = *(const bf16x8*)((const char*)Bs + swz(wc * 64 + n * 16 + l15, ks * 64 + lk * 16));
#pragma unroll
      for (int m = 0; m < 4; ++m)
#pragma unroll
        for (int n = 0; n < 4; ++n)
          acc[m][n] = __builtin_amdgcn_mfma_f32_16x16x32_bf16(a[m], b[n], acc[m][n], 0, 0, 0);
    }
    __syncthreads();
  }

  // epilogue: D = sqi + sqj - 2c ; K = sum_b exp(-D/b) via 1 exp2 + squarings
  const float c80 = 0.01803368801f;  // log2(e)/80
  float sqi[16], sqj[4];
#pragma unroll
  for (int m = 0; m < 4; ++m)
#pragma unroll
    for (int r = 0; r < 4; ++r) sqi[m * 4 + r] = SQi[wr * 64 + m * 16 + lk * 4 + r];
#pragma unroll
  for (int n = 0; n < 4; ++n) sqj[n] = SQj[wc * 64 + n * 16 + l15];

  bool diag = (it == jt);
  float lsum = 0.f;
#pragma unroll
  for (int m = 0; m < 4; ++m) {
#pragma unroll
    for (int n = 0; n < 4; ++n) {
#pragma unroll
      for (int r = 0; r < 4; ++r) {
        float cv = acc[m][n][r];
        float D = sqi[m * 4 + r] + sqj[n] - 2.f * cv;
        float e80 = exp2f(-c80 * D);     // exp(-D/80)
        float e40 = e80 * e80;
        float e20 = e40 * e40;
        float e10 = e20 * e20;
        float e5  = e10 * e10;
        float e2  = e5 * e5 * e10;       // exp(-D/2)
        float K = (e80 + e40) + (e20 + e10) + (e5 + e2);
        if (diag) {
          int gi = wr * 64 + m * 16 + lk * 4 + r;
          int gj = wc * 64 + n * 16 + l15;
          if (gi == gj) K = 6.0f;        // D==0 exactly on the diagonal
        }
        lsum += K;
      }
    }
  }
#pragma unroll
  for (int off = 32; off; off >>= 1) lsum += __shfl_down(lsum, off, 64);
  if (lane == 0) wsum[w] = lsum;
  __syncthreads();
  if (t == 0) {
    float sgn = ((it < 2) == (jt < 2)) ? 1.0f : -1.0f;
    float wgt = sgn * ((it == jt) ? 1.0f : 2.0f);   // off-diag tiles count twice
    part[bx] = wgt * (wsum[0] + wsum[1] + wsum[2] + wsum[3]);
  }
}

// ---------------------------------------------------------------------------
// Kernel 4: deterministic final reduce of 2560 partials -> mean
// ---------------------------------------------------------------------------
__global__ __launch_bounds__(256) void k_reduce(const float* __restrict__ part,
                                                float* __restrict__ out) {
  __shared__ float wsum[4];
  int t = threadIdx.x;
  float s = 0.f;
#pragma unroll
  for (int i = 0; i < 10; ++i) s += part[i * 256 + t];
#pragma unroll
  for (int off = 32; off; off >>= 1) s += __shfl_down(s, off, 64);
  int lane = t & 63, w = t >> 6;
  if (lane == 0) wsum[w] = s;
  __syncthreads();
  if (t == 0) out[0] = (wsum[0] + wsum[1] + wsum[2] + wsum[3]) * (1.0f / 16777216.0f);
}

extern "C" void kernel_launch(void* const* d_in, const int* in_sizes, int n_in,
                              void* d_out, int out_size, void* d_ws, size_t ws_size,
                              hipStream_t stream) {
  (void)in_sizes; (void)n_in; (void)out_size; (void)ws_size;
  const float* src = (const float*)d_in[0];
  const float* tgt = (const float*)d_in[1];
  char* ws = (char*)d_ws;
  unsigned short* X = (unsigned short*)ws;                    // 67,108,864 B
  float* SQ   = (float*)(ws + 67108864);                      //    524,288 B
  float* PART = (float*)(ws + 67108864 + 524288);             //     10,240 B

  hipLaunchKernelGGL(k_repack, dim3(8192),  dim3(256), 0, stream, src, tgt, X);
  hipLaunchKernelGGL(k_sq,     dim3(16384), dim3(256), 0, stream, X, SQ);
  hipLaunchKernelGGL(k_mmd,    dim3(2560),  dim3(256), 0, stream, X, SQ, PART);
  hipLaunchKernelGGL(k_reduce, dim3(1),     dim3(256), 0, stream, PART, (float*)d_out);
}